// Round 6
// baseline (64.711 us; speedup 1.0000x reference)
//
#include <hip/hip_runtime.h>

#define PI_F 3.14159265358979323846f

#define D0 768
#define D1 512
#define D2 1024
#define WT_FLOATS 13824
#define U_OFF   WT_FLOATS          // 12 gates * 4 floats (u00r,u00i,u01r,u01i)
#define CRY_OFF (WT_FLOATS + 48)   // 6 * 2 floats (c,s)

// force value materialized here; memory clobber pins load issue order across this point
#define KEEP4(v) asm volatile("" : "+v"(v.x), "+v"(v.y), "+v"(v.z), "+v"(v.w) : : "memory")

// ---------------- prep: W^T transpose + uniform gate constants ----------------

__global__ void prep_kernel(const float* __restrict__ W0, const float* __restrict__ W1,
                            const float* __restrict__ W2, const float* __restrict__ qw,
                            float* __restrict__ ws) {
    int t = blockIdx.x * 256 + threadIdx.x;
    if (t < 4608) {
        int j = t / 768, k = t - j * 768;
        ws[t] = W0[k * 6 + j];
    } else if (t < 7680) {
        int u = t - 4608, j = u / 512, k = u - j * 512;
        ws[t] = W1[k * 6 + j];
    } else if (t < WT_FLOATS) {
        int u = t - 7680, j = u / 1024, k = u - j * 1024;
        ws[t] = W2[k * 6 + j];
    } else if (t < WT_FLOATS + 12) {
        int g = t - WT_FLOATS;  // g = layer*6 + qubit
        float ca, sa, cb, sb, cc, sc;
        sincosf(0.5f * qw[g * 3 + 0], &sa, &ca);
        sincosf(0.5f * qw[g * 3 + 1], &sb, &cb);
        sincosf(0.5f * qw[g * 3 + 2], &sc, &cc);
        // U = Rz(g) * Ry(b) * Rx(a); SU(2): row0 = (u00, u01)
        float m00r = cb * ca, m00i = sb * sa;
        float m01r = -sb * ca, m01i = -cb * sa;
        float* u4 = ws + U_OFF + g * 4;
        u4[0] = m00r * cc + m00i * sc;
        u4[1] = m00i * cc - m00r * sc;
        u4[2] = m01r * cc + m01i * sc;
        u4[3] = m01i * cc - m01r * sc;
    } else if (t < WT_FLOATS + 18) {
        int k = t - WT_FLOATS - 12;   // k = layer*3 + pair
        int l = k / 3, i = (k - l * 3) * 2;
        float c, s;
        sincosf(0.5f * qw[(l * 6 + i) * 3 + 1], &s, &c);
        ws[CRY_OFF + k * 2 + 0] = c;
        ws[CRY_OFF + k * 2 + 1] = s;
    }
}

// ---------------- cross-lane primitives ----------------

template<int CTRL>
__device__ __forceinline__ float dppmov(float v) {
    return __int_as_float(__builtin_amdgcn_update_dpp(0, __float_as_int(v), CTRL, 0xF, 0xF, true));
}
template<int PAT>
__device__ __forceinline__ float swzf(float v) {
    return __int_as_float(__builtin_amdgcn_ds_swizzle(__float_as_int(v), PAT));
}

template<int M>
__device__ __forceinline__ float xsh(float v) {
    if constexpr (M == 1)       return dppmov<0xB1>(v);   // quad_perm [1,0,3,2]
    else if constexpr (M == 2)  return dppmov<0x4E>(v);   // quad_perm [2,3,0,1]
    else if constexpr (M == 4)  return swzf<0x101F>(v);   // ds_swizzle xor 4
    else if constexpr (M == 8)  return dppmov<0x128>(v);  // row_ror:8 == xor 8
    else if constexpr (M == 16) return swzf<0x401F>(v);   // ds_swizzle xor 16
    else                        return __shfl_xor(v, 32, 64);
}

__device__ __forceinline__ float pl16_sum(float v) {
#if __has_builtin(__builtin_amdgcn_permlane16_swap)
    auto r = __builtin_amdgcn_permlane16_swap(__float_as_uint(v), __float_as_uint(v), false, false);
    return __uint_as_float(r[0]) + __uint_as_float(r[1]);
#else
    return v + swzf<0x401F>(v);
#endif
}
__device__ __forceinline__ float pl32_sum(float v) {
#if __has_builtin(__builtin_amdgcn_permlane32_swap)
    auto r = __builtin_amdgcn_permlane32_swap(__float_as_uint(v), __float_as_uint(v), false, false);
    return __uint_as_float(r[0]) + __uint_as_float(r[1]);
#else
    return v + __shfl_xor(v, 32, 64);
#endif
}

__device__ __forceinline__ float fast_tanh(float x) {
    float e = __expf(2.0f * x);
    return 1.0f - 2.0f / (e + 1.0f);
}

__device__ __forceinline__ float dot4(float4 a, float4 w, float acc) {
    return fmaf(a.x, w.x, fmaf(a.y, w.y, fmaf(a.z, w.z, fmaf(a.w, w.w, acc))));
}

// ---------------- gates (2 states/wave, lane = basis state; qubit i <-> bit 5-i) ----------------

template<int M>
__device__ __forceinline__ void gateU(float (&re)[2], float (&im)[2], int lane,
                                      float ar, float ai, float br, float bi) {
    const bool hi = (lane & M) != 0;
    const float Ai = hi ? -ai : ai;
    const float Br = hi ? -br : br;
#pragma unroll
    for (int s = 0; s < 2; ++s) {
        float pre = xsh<M>(re[s]);
        float pim = xsh<M>(im[s]);
        float nr = ar * re[s] - Ai * im[s] + Br * pre - bi * pim;
        float ni = ar * im[s] + Ai * re[s] + Br * pim + bi * pre;
        re[s] = nr; im[s] = ni;
    }
}

template<int MC, int MT>
__device__ __forceinline__ void gateCRY(float (&re)[2], float (&im)[2], int lane, float c, float sn) {
    const bool c1 = (lane & MC) != 0;
    const float sg = (lane & MT) ? sn : -sn;
#pragma unroll
    for (int s = 0; s < 2; ++s) {
        float pre = xsh<MT>(re[s]);
        float pim = xsh<MT>(im[s]);
        float nr = fmaf(c, re[s], sg * pre);
        float ni = fmaf(c, im[s], sg * pim);
        re[s] = c1 ? nr : re[s];
        im[s] = c1 ? ni : im[s];
    }
}

template<int I>
__device__ __forceinline__ void l1gate(float (&re)[2], float (&im)[2], int lane,
                                       const float* __restrict__ ws) {
    constexpr int M = 32 >> I;
    const float ar = ws[U_OFF + (6 + I) * 4 + 0];
    const float ai = ws[U_OFF + (6 + I) * 4 + 1];
    const float br = ws[U_OFF + (6 + I) * 4 + 2];
    const float bi = ws[U_OFF + (6 + I) * 4 + 3];
    gateU<M>(re, im, lane, ar, ai, br, bi);
}

template<int L, int P>
__device__ __forceinline__ void cryGate(float (&re)[2], float (&im)[2], int lane,
                                        const float* __restrict__ ws) {
    constexpr int MC = 32 >> (2 * P);
    constexpr int MT = 16 >> (2 * P);
    const float c = ws[CRY_OFF + (L * 3 + P) * 2 + 0];
    const float s = ws[CRY_OFF + (L * 3 + P) * 2 + 1];
    gateCRY<MC, MT>(re, im, lane, c, s);
}

// encoding RY(ang) followed by layer-0 RX/RY/RZ: product state -> build directly
__device__ __forceinline__ void buildState(const float (&ang)[6], int lane,
                                           const float* __restrict__ ws,
                                           float& reO, float& imO) {
    float pr, pi;
#pragma unroll
    for (int i = 0; i < 6; ++i) {
        float cq, sq;
        __sincosf(0.5f * ang[i], &sq, &cq);
        const float ar = ws[U_OFF + i * 4 + 0];
        const float ai = ws[U_OFF + i * 4 + 1];
        const float br = ws[U_OFF + i * 4 + 2];
        const float bi = ws[U_OFF + i * 4 + 3];
        float vloR = ar * cq + br * sq;
        float vloI = ai * cq + bi * sq;
        float vhiR = ar * sq - br * cq;
        float vhiI = bi * cq - ai * sq;
        bool hi = (lane & (32 >> i)) != 0;
        float vr = hi ? vhiR : vloR;
        float vi = hi ? vhiI : vloI;
        if (i == 0) { pr = vr; pi = vi; }
        else { float t = pr * vr - pi * vi; pi = pr * vi + pi * vr; pr = t; }
    }
    reO = pr; imO = pi;
}

// ---------------- main kernel ----------------

__global__ __launch_bounds__(256, 3) void qf_main(
    const float* __restrict__ f0, const float* __restrict__ b0,
    const float* __restrict__ f1, const float* __restrict__ b1,
    const float* __restrict__ f2, const float* __restrict__ b2,
    const float* __restrict__ fl, const float* __restrict__ ws,
    float* __restrict__ out)
{
    const int lane = threadIdx.x & 63;
    const int wave = blockIdx.x * 4 + (threadIdx.x >> 6);  // 8192 waves
    const int s0 = wave * 2;

    // fusion softmax first (scalar pipe, before the memory-clobber fences)
    float l0 = fl[0], l1 = fl[1], l2 = fl[2];
    float mx = fmaxf(l0, fmaxf(l1, l2));
    float e0 = __expf(l0 - mx), e1 = __expf(l1 - mx), e2 = __expf(l2 - mx);
    float inv = 1.0f / (e0 + e1 + e2);
    float fw0 = e0 * inv, fw1 = e1 * inv, fw2 = e2 * inv;

    const float4* __restrict__ xA0 = (const float4*)(f0 + (size_t)s0 * D0);
    const float4* __restrict__ xB0 = (const float4*)(f0 + (size_t)(s0 + 1) * D0);
    const float4* __restrict__ xA1 = (const float4*)(f1 + (size_t)s0 * D1);
    const float4* __restrict__ xB1 = (const float4*)(f1 + (size_t)(s0 + 1) * D1);
    const float4* __restrict__ xA2 = (const float4*)(f2 + (size_t)s0 * D2);
    const float4* __restrict__ xB2 = (const float4*)(f2 + (size_t)(s0 + 1) * D2);

    // ---- issue ALL 18 x-loads up-front, in drain order m0 -> m1 -> m2 ----
    float4 xa0 = xA0[lane], xa1 = xA0[64 + lane], xa2 = xA0[128 + lane];
    float4 xb0 = xB0[lane], xb1 = xB0[64 + lane], xb2 = xB0[128 + lane];
    float4 xa3 = xA1[lane], xa4 = xA1[64 + lane];
    float4 xb3 = xB1[lane], xb4 = xB1[64 + lane];
    float4 xa5 = xA2[lane], xa6 = xA2[64 + lane], xa7 = xA2[128 + lane], xa8 = xA2[192 + lane];
    float4 xb5 = xB2[lane], xb6 = xB2[64 + lane], xb7 = xB2[128 + lane], xb8 = xB2[192 + lane];

    // ---- drain stage 1: materialize m0 x only (m1/m2 remain in flight) ----
    KEEP4(xa0); KEEP4(xa1); KEEP4(xa2); KEEP4(xb0); KEEP4(xb1); KEEP4(xb2);

    const float4* __restrict__ w4 = (const float4*)ws;
    float r[36];  // m0 A=0..5 B=6..11, m1 A=12..17 B=18..23, m2 A=24..29 B=30..35

    // ---- modality 0 FMAs ----
#pragma unroll
    for (int j = 0; j < 6; ++j) {
        float4 w0 = w4[j * 192 + lane];
        float4 w1 = w4[j * 192 + 64 + lane];
        float4 w2 = w4[j * 192 + 128 + lane];
        float a = 0.f, b = 0.f;
        a = dot4(xa0, w0, a); a = dot4(xa1, w1, a); a = dot4(xa2, w2, a);
        b = dot4(xb0, w0, b); b = dot4(xb1, w1, b); b = dot4(xb2, w2, b);
        r[j] = a; r[6 + j] = b;
    }

    // ---- drain stage 2: materialize m1 x ----
    KEEP4(xa3); KEEP4(xa4); KEEP4(xb3); KEEP4(xb4);

#pragma unroll
    for (int j = 0; j < 6; ++j) {
        float4 w0 = w4[1152 + j * 128 + lane];
        float4 w1 = w4[1152 + j * 128 + 64 + lane];
        float a = 0.f, b = 0.f;
        a = dot4(xa3, w0, a); a = dot4(xa4, w1, a);
        b = dot4(xb3, w0, b); b = dot4(xb4, w1, b);
        r[12 + j] = a; r[18 + j] = b;
    }

    // ---- drain stage 3: materialize m2 x ----
    KEEP4(xa5); KEEP4(xa6); KEEP4(xa7); KEEP4(xa8);
    KEEP4(xb5); KEEP4(xb6); KEEP4(xb7); KEEP4(xb8);

#pragma unroll
    for (int j = 0; j < 6; ++j) {
        float4 w0 = w4[1920 + j * 256 + lane];
        float4 w1 = w4[1920 + j * 256 + 64 + lane];
        float4 w2 = w4[1920 + j * 256 + 128 + lane];
        float4 w3 = w4[1920 + j * 256 + 192 + lane];
        float a = 0.f, b = 0.f;
        a = dot4(xa5, w0, a); a = dot4(xa6, w1, a); a = dot4(xa7, w2, a); a = dot4(xa8, w3, a);
        b = dot4(xb5, w0, b); b = dot4(xb6, w1, b); b = dot4(xb7, w2, b); b = dot4(xb8, w3, b);
        r[24 + j] = a; r[30 + j] = b;
    }

    // ---- batched 64-lane reductions: 6 passes, 36-way ILP each ----
#pragma unroll
    for (int k = 0; k < 36; ++k) r[k] += dppmov<0xB1>(r[k]);
#pragma unroll
    for (int k = 0; k < 36; ++k) r[k] += dppmov<0x4E>(r[k]);
#pragma unroll
    for (int k = 0; k < 36; ++k) r[k] += swzf<0x101F>(r[k]);
#pragma unroll
    for (int k = 0; k < 36; ++k) r[k] += dppmov<0x128>(r[k]);
#pragma unroll
    for (int k = 0; k < 36; ++k) r[k] = pl16_sum(r[k]);
#pragma unroll
    for (int k = 0; k < 36; ++k) r[k] = pl32_sum(r[k]);

    // ---- batched tanh + combine ----
    float angA[6], angB[6];
#pragma unroll
    for (int j = 0; j < 6; ++j) {
        float tA0 = fast_tanh(r[j]      + b0[j]);
        float tB0 = fast_tanh(r[6 + j]  + b0[j]);
        float tA1 = fast_tanh(r[12 + j] + b1[j]);
        float tB1 = fast_tanh(r[18 + j] + b1[j]);
        float tA2 = fast_tanh(r[24 + j] + b2[j]);
        float tB2 = fast_tanh(r[30 + j] + b2[j]);
        angA[j] = PI_F * (fw0 * tA0 + fw1 * tA1 + fw2 * tA2);
        angB[j] = PI_F * (fw0 * tB0 + fw1 * tB1 + fw2 * tB2);
    }

    // ---- circuit ----
    // CNOT chain collapses to one lane permutation: sigma = l ^ ((l>>1)&0x1F) ^ ((l>>5)&1)
    const int sigma = lane ^ ((lane >> 1) & 0x1F) ^ ((lane >> 5) & 1);

    float re[2], im[2];
    buildState(angA, lane, ws, re[0], im[0]);  // encoding + layer-0 rotations fused
    buildState(angB, lane, ws, re[1], im[1]);

    re[0] = __shfl(re[0], sigma, 64); im[0] = __shfl(im[0], sigma, 64);
    re[1] = __shfl(re[1], sigma, 64); im[1] = __shfl(im[1], sigma, 64);
    cryGate<0,0>(re, im, lane, ws); cryGate<0,1>(re, im, lane, ws); cryGate<0,2>(re, im, lane, ws);

    l1gate<0>(re, im, lane, ws); l1gate<1>(re, im, lane, ws); l1gate<2>(re, im, lane, ws);
    l1gate<3>(re, im, lane, ws); l1gate<4>(re, im, lane, ws); l1gate<5>(re, im, lane, ws);
    re[0] = __shfl(re[0], sigma, 64); im[0] = __shfl(im[0], sigma, 64);
    re[1] = __shfl(re[1], sigma, 64); im[1] = __shfl(im[1], sigma, 64);
    cryGate<1,0>(re, im, lane, ws); cryGate<1,1>(re, im, lane, ws); cryGate<1,2>(re, im, lane, ws);

    // ---- measurement: FWHT; lane (32>>i) holds z_i ----
#pragma unroll
    for (int s = 0; s < 2; ++s) {
        float p = fmaf(re[s], re[s], im[s] * im[s]);
        float q;
        q = xsh<1>(p);  p = (lane & 1)  ? (q - p) : (p + q);
        q = xsh<2>(p);  p = (lane & 2)  ? (q - p) : (p + q);
        q = xsh<4>(p);  p = (lane & 4)  ? (q - p) : (p + q);
        q = xsh<8>(p);  p = (lane & 8)  ? (q - p) : (p + q);
        q = xsh<16>(p); p = (lane & 16) ? (q - p) : (p + q);
        q = xsh<32>(p); p = (lane & 32) ? (q - p) : (p + q);
        if (__popc(lane) == 1)
            out[(size_t)(s0 + s) * 6 + (6 - __ffs(lane))] = p;
    }
}

extern "C" void kernel_launch(void* const* d_in, const int* in_sizes, int n_in,
                              void* d_out, int out_size, void* d_ws, size_t ws_size,
                              hipStream_t stream) {
    const float* f0 = (const float*)d_in[0];
    const float* W0 = (const float*)d_in[1];
    const float* b0 = (const float*)d_in[2];
    const float* f1 = (const float*)d_in[3];
    const float* W1 = (const float*)d_in[4];
    const float* b1 = (const float*)d_in[5];
    const float* f2 = (const float*)d_in[6];
    const float* W2 = (const float*)d_in[7];
    const float* b2 = (const float*)d_in[8];
    const float* qw = (const float*)d_in[9];
    const float* fl = (const float*)d_in[10];
    float* out = (float*)d_out;
    float* ws = (float*)d_ws;  // 13842 floats used

    prep_kernel<<<55, 256, 0, stream>>>(W0, W1, W2, qw, ws);
    qf_main<<<2048, 256, 0, stream>>>(f0, b0, f1, b1, f2, b2, fl, ws, out);
}